// Round 4
// baseline (362.524 us; speedup 1.0000x reference)
//
#include <hip/hip_runtime.h>
#include <stdint.h>

#define BATCH  2048
#define HID    512
#define CAP    65536
#define NHASH  8
#define TOPK   32
#define NSLICE 16
#define SLICE_SZ (CAP / NSLICE)   // 4096
#define NROWS  (BATCH + CAP)      // 67584 rows to hash
#define HGRID  512                // 2048 waves, 33 rows/wave exactly

typedef unsigned int   u32;
typedef unsigned long long u64;

// ---------------------------------------------------------------------------
// K_prep: fuses three independent prologue jobs into one launch:
//   blocks 0-1 : hist16 zero + Psum[h][n] = sum_d P[n][h][d] (f64)
//   blocks 2-65: out_w transpose [o][h] -> wt [h][o]
// ---------------------------------------------------------------------------
__global__ __launch_bounds__(256) void k_prep(const float* __restrict__ proj,
                                              double* __restrict__ psumT,
                                              u32* __restrict__ hist16,
                                              const float* __restrict__ w,
                                              float* __restrict__ wt) {
    __shared__ float tile[64][65];
    int bi = blockIdx.x, tid = threadIdx.x;
    if (bi < 2) {
        int g = bi * 256 + tid;                   // 0..511
        for (int i = g; i < NSLICE * 256; i += 512) hist16[i] = 0;
        int h = g;                                // h < HID (=512) always
        for (int n = 0; n < NHASH; n++) {
            const float* p = proj + ((size_t)n * HID + h) * 16;
            double s = 0.0;
            #pragma unroll
            for (int d = 0; d < 16; d++) s += (double)p[d];
            psumT[(size_t)h * NHASH + n] = s;
        }
    } else {
        int b = bi - 2, bx = b & 7, by = b >> 3;
        int tx = tid & 63, ty = tid >> 6;
        for (int r = ty; r < 64; r += 4)
            tile[r][tx] = w[(size_t)(by * 64 + r) * HID + bx * 64 + tx];
        __syncthreads();
        for (int r = ty; r < 64; r += 4)
            wt[(size_t)(bx * 64 + r) * HID + by * 64 + tx] = tile[tx][r];
    }
}

// ---------------------------------------------------------------------------
// K_hash, VALU streaming form (replaces the f64-MFMA tile engine).
// The op is a [NROWS x 512] x [512 x 8] sign-GEMM = 545 MFLOP over 132 MB:
// pure streaming. Wave-per-row:
//   - lane l holds Psum[8l+j][n] (j,n in 0..7) in 128 VGPRs, loaded once
//   - per row: 2 coalesced float4 loads (32 B/lane = whole 2 KB row),
//     64 unrolled f64 FMAs into acc[8] (same f64 sums as before -> sign-safe)
//   - butterfly folds the n-dim into lane bits (xor 1/2/4), then plain
//     reduce over xor 8/16/32: lane c ends with the total for n=c, so
//     __ballot(v>0) & 0xFF IS the hash byte. 10 f64 shuffles total.
//   - next-row prefetch in named float4 regs (no indexed array -> no scratch)
// No LDS, no barriers, no MFMA. Expected ~HBM-bound (~132 MB / 6.9 TB/s).
// ---------------------------------------------------------------------------
__global__ __launch_bounds__(256, 2) void k_hash(const float* __restrict__ query,
                                                 const float* __restrict__ keys,
                                                 const double* __restrict__ psumT,
                                                 unsigned char* __restrict__ qhash,
                                                 unsigned char* __restrict__ khash,
                                                 u32* __restrict__ hist16) {
    const int lane = threadIdx.x & 63;
    const int W    = (blockIdx.x << 2) | (threadIdx.x >> 6);   // global wave id
    const int NW   = HGRID << 2;                               // 2048 waves

    // per-lane Psum slice: P[j][n] = psumT[(8*lane+j)*8 + n] (contiguous 64)
    double P[8][8];
    {
        const double* pp = psumT + ((size_t)lane << 6);
        #pragma unroll
        for (int j = 0; j < 8; j++)
            #pragma unroll
            for (int n = 0; n < 8; n++)
                P[j][n] = pp[j * 8 + n];
    }

    const int sel1 = lane & 1, sel2 = (lane >> 1) & 1, sel3 = (lane >> 2) & 1;

    int r = W;
    float4 xa, xb;
    if (r < NROWS) {
        const float* xp = (r < BATCH) ? (query + (size_t)r * HID)
                                      : (keys + (size_t)(r - BATCH) * HID);
        const float4* v4 = (const float4*)xp + (lane << 1);
        xa = v4[0]; xb = v4[1];
    }
    while (r < NROWS) {
        const int rn = r + NW;
        float4 na, nb;
        if (rn < NROWS) {   // prefetch next row early; lands during FMAs
            const float* xp = (rn < BATCH) ? (query + (size_t)rn * HID)
                                           : (keys + (size_t)(rn - BATCH) * HID);
            const float4* v4 = (const float4*)xp + (lane << 1);
            na = v4[0]; nb = v4[1];
        }

        double acc[8];
        #pragma unroll
        for (int n = 0; n < 8; n++) acc[n] = 0.0;
        {
            float xf0 = xa.x, xf1 = xa.y, xf2 = xa.z, xf3 = xa.w;
            float xf4 = xb.x, xf5 = xb.y, xf6 = xb.z, xf7 = xb.w;
            double xd;
            xd = (double)xf0;
            #pragma unroll
            for (int n = 0; n < 8; n++) acc[n] = fma(xd, P[0][n], acc[n]);
            xd = (double)xf1;
            #pragma unroll
            for (int n = 0; n < 8; n++) acc[n] = fma(xd, P[1][n], acc[n]);
            xd = (double)xf2;
            #pragma unroll
            for (int n = 0; n < 8; n++) acc[n] = fma(xd, P[2][n], acc[n]);
            xd = (double)xf3;
            #pragma unroll
            for (int n = 0; n < 8; n++) acc[n] = fma(xd, P[3][n], acc[n]);
            xd = (double)xf4;
            #pragma unroll
            for (int n = 0; n < 8; n++) acc[n] = fma(xd, P[4][n], acc[n]);
            xd = (double)xf5;
            #pragma unroll
            for (int n = 0; n < 8; n++) acc[n] = fma(xd, P[5][n], acc[n]);
            xd = (double)xf6;
            #pragma unroll
            for (int n = 0; n < 8; n++) acc[n] = fma(xd, P[6][n], acc[n]);
            xd = (double)xf7;
            #pragma unroll
            for (int n = 0; n < 8; n++) acc[n] = fma(xd, P[7][n], acc[n]);
        }

        // fold n into lane bits: after 3 steps lane holds total for n = lane&7
        double t4[4];
        #pragma unroll
        for (int i = 0; i < 4; i++) {
            double a0 = acc[2 * i], a1 = acc[2 * i + 1];
            double keep = sel1 ? a1 : a0;
            double give = sel1 ? a0 : a1;
            t4[i] = keep + __shfl_xor(give, 1, 64);    // n = 2i + sel1
        }
        double t2[2];
        #pragma unroll
        for (int i = 0; i < 2; i++) {
            double a0 = t4[2 * i], a1 = t4[2 * i + 1];
            double keep = sel2 ? a1 : a0;
            double give = sel2 ? a0 : a1;
            t2[i] = keep + __shfl_xor(give, 2, 64);    // n = 4i + 2*sel2 + sel1
        }
        double keep = sel3 ? t2[1] : t2[0];
        double give = sel3 ? t2[0] : t2[1];
        double v = keep + __shfl_xor(give, 4, 64);     // n = lane & 7
        v += __shfl_xor(v, 8, 64);
        v += __shfl_xor(v, 16, 64);
        v += __shfl_xor(v, 32, 64);

        u64 bm = __ballot(v > 0.0);                    // bits 0..7 = byte
        if (lane == 0) {
            u32 byte = (u32)(bm & 0xFFull);
            if (r < BATCH) {
                qhash[r] = (unsigned char)byte;
            } else {
                int kr = r - BATCH;
                khash[kr] = (unsigned char)byte;
                atomicAdd(&hist16[(kr >> 12) * 256 + byte], 1u);
            }
        }
        xa = na; xb = nb;
        r = rn;
    }
}

// ---------------------------------------------------------------------------
// K_scan: parallel prefix sums (shuffle-based).
// ---------------------------------------------------------------------------
__global__ __launch_bounds__(256) void k_scan(const u32* __restrict__ hist16,
                                              u32* __restrict__ bucketCnt,
                                              u32* __restrict__ bucketOff,
                                              u32* __restrict__ off16) {
    __shared__ u32 wsum[4];
    int v = threadIdx.x, lane = v & 63, wv = v >> 6;
    u32 tot = 0;
    for (int s = 0; s < NSLICE; s++) tot += hist16[s * 256 + v];
    bucketCnt[v] = tot;
    u32 inc = tot;
    #pragma unroll
    for (int s = 1; s < 64; s <<= 1) {
        u32 n = __shfl_up(inc, s, 64);
        if (lane >= s) inc += n;
    }
    if (lane == 63) wsum[wv] = inc;
    __syncthreads();
    u32 wof = 0;
    for (int i = 0; i < wv; i++) wof += wsum[i];
    u32 base = wof + inc - tot;          // exclusive prefix over buckets
    bucketOff[v] = base;
    for (int s = 0; s < NSLICE; s++) { off16[s * 256 + v] = base; base += hist16[s * 256 + v]; }
}

// ---------------------------------------------------------------------------
// K_compact: stable compaction: bucketList sorted by (hash byte, index asc).
// ---------------------------------------------------------------------------
__global__ __launch_bounds__(256) void k_compact(const unsigned char* __restrict__ khash,
                                                 const u32* __restrict__ off16,
                                                 u32* __restrict__ bucketList) {
    __shared__ unsigned char sh[SLICE_SZ];
    int s  = blockIdx.x & (NSLICE - 1);
    int bg = blockIdx.x >> 4;
    ((uint4*)sh)[threadIdx.x] = ((const uint4*)(khash + (size_t)s * SLICE_SZ))[threadIdx.x];
    __syncthreads();
    int w = threadIdx.x >> 6, lane = threadIdx.x & 63;
    int v = bg * 4 + w;
    u32 base = off16[s * 256 + v];
    for (int i = 0; i < SLICE_SZ / 64; i++) {
        int c = i * 64 + lane;
        unsigned char byte = sh[c];
        bool hit = (byte == (unsigned char)v);
        u64 m = __ballot(hit);
        if (hit) {
            int rank = __popcll(m & ((1ull << lane) - 1ull));
            bucketList[base + rank] = (u32)(s * SLICE_SZ + c);
        }
        base += (u32)__popcll(m);
    }
}

// ---------------------------------------------------------------------------
// K_attn: FUSED top-32 selection (wave 0, into LDS) + gather + scores +
// softmax + weighted V sum. Block per query.
// ---------------------------------------------------------------------------
__global__ __launch_bounds__(256) void k_attn(const float* __restrict__ keys,
                                              const float* __restrict__ vals,
                                              const float* __restrict__ query,
                                              const unsigned char* __restrict__ qhash,
                                              const u32* __restrict__ bucketCnt,
                                              const u32* __restrict__ bucketOff,
                                              const u32* __restrict__ bucketList,
                                              float* __restrict__ mo) {
    __shared__ int sIdx[TOPK];
    __shared__ float sSc[TOPK], sE[TOPK];
    __shared__ int sPos0;
    int b = blockIdx.x, tid = threadIdx.x;
    int w = tid >> 6, lane = tid & 63;

    // ---- selection: wave 0 only (per-query top-32 by (hamming dist, idx)) ----
    if (w == 0) {
        if (lane == 0) sPos0 = 0;
        u32 qh = qhash[b];

        int d[4]; u32 cnt[4], off[4];
        #pragma unroll
        for (int jj = 0; jj < 4; jj++) {
            int v = lane + jj * 64;
            d[jj] = __popc(qh ^ (u32)v);
            cnt[jj] = bucketCnt[v];
            off[jj] = bucketOff[v];
        }

        u32 ct[9];
        #pragma unroll
        for (int t = 0; t < 9; t++) {
            u32 c = 0;
            #pragma unroll
            for (int jj = 0; jj < 4; jj++) c += (d[jj] == t) ? cnt[jj] : 0u;
            #pragma unroll
            for (int s = 32; s >= 1; s >>= 1) c += __shfl_xor(c, s, 64);
            ct[t] = c;
        }

        int dcut = 0; u32 run = 0, before = 0;
        for (int t = 0; t < 9; t++) {
            before = run; run += ct[t];
            if (run >= TOPK) { dcut = t; break; }
        }
        int need = TOPK - (int)before;

        #pragma unroll
        for (int jj = 0; jj < 4; jj++) {
            if (d[jj] < dcut && cnt[jj] > 0) {
                int base = atomicAdd(&sPos0, (int)cnt[jj]);
                for (u32 e = 0; e < cnt[jj]; e++)
                    sIdx[base + e] = (int)bucketList[off[jj] + e];
            }
        }

        int nb = 0;
        #pragma unroll
        for (int jj = 0; jj < 4; jj++) nb += (d[jj] == dcut) ? 1 : 0;
        #pragma unroll
        for (int s = 32; s >= 1; s >>= 1) nb += __shfl_xor(nb, s, 64);

        if (nb == 1) {
            u32 boff = 0xFFFFFFFFu;
            #pragma unroll
            for (int jj = 0; jj < 4; jj++) if (d[jj] == dcut) boff = off[jj];
            #pragma unroll
            for (int s = 32; s >= 1; s >>= 1) boff = min(boff, __shfl_xor(boff, s, 64));
            if (lane < need)
                sIdx[(int)before + lane] = (int)bucketList[boff + lane];
        } else {
            u32 pos[4], end[4]; int val[4];
            #pragma unroll
            for (int jj = 0; jj < 4; jj++) {
                if (d[jj] == dcut && cnt[jj] > 0) {
                    pos[jj] = off[jj]; end[jj] = off[jj] + cnt[jj];
                    val[jj] = (int)bucketList[pos[jj]];
                } else { pos[jj] = 0; end[jj] = 0; val[jj] = 0x7fffffff; }
            }
            for (int it = 0; it < need; it++) {
                int m = min(min(val[0], val[1]), min(val[2], val[3]));
                int g = m;
                #pragma unroll
                for (int s = 32; s >= 1; s >>= 1) g = min(g, __shfl_xor(g, s, 64));
                if (lane == 0) sIdx[(int)before + it] = g;
                if (m == g && g != 0x7fffffff) {
                    #pragma unroll
                    for (int jj = 0; jj < 4; jj++) {
                        if (val[jj] == g) {
                            pos[jj]++;
                            val[jj] = (pos[jj] < end[jj]) ? (int)bucketList[pos[jj]] : 0x7fffffff;
                            break;
                        }
                    }
                }
            }
        }
    }
    __syncthreads();

    // ---- scores: wave w handles keys [8w, 8w+8) ----
    const float4* qp = (const float4*)(query + (size_t)b * HID + lane * 8);
    float4 qa = qp[0], qb = qp[1];

    for (int i = w * 8; i < w * 8 + 8; i++) {
        int idx = sIdx[i];
        const float4* kp = (const float4*)(keys + (size_t)idx * HID + lane * 8);
        float4 ka = kp[0], kb = kp[1];
        float dot = qa.x * ka.x + qa.y * ka.y + qa.z * ka.z + qa.w * ka.w
                  + qb.x * kb.x + qb.y * kb.y + qb.z * kb.z + qb.w * kb.w;
        #pragma unroll
        for (int s = 32; s >= 1; s >>= 1) dot += __shfl_xor(dot, s, 64);
        if (lane == 0) sSc[i] = dot * 0.04419417382415922f;  // 1/sqrt(512)
    }
    __syncthreads();

    if (tid < TOPK) {
        float m = -1e30f;
        for (int i = 0; i < TOPK; i++) m = fmaxf(m, sSc[i]);
        sE[tid] = expf(sSc[tid] - m);
    }
    __syncthreads();

    float sum = 0.f;
    for (int i = 0; i < TOPK; i++) sum += sE[i];
    float inv = 1.0f / sum;

    // ---- weighted V sum: float2 per thread (8 B/lane coalescing) ----
    int h0 = tid * 2;
    float a0 = 0.f, a1 = 0.f;
    for (int i = 0; i < TOPK; i++) {
        int idx = sIdx[i];
        float e = sE[i];
        float2 vv = *(const float2*)(vals + (size_t)idx * HID + h0);
        a0 += e * vv.x; a1 += e * vv.y;
    }
    ((float2*)(mo + (size_t)b * HID))[tid] = make_float2(a0 * inv, a1 * inv);
}

// ---------------------------------------------------------------------------
// K_proj: out[b][o] = sum_h mo[b][h] * wt[h][o] + bias[o]; 8 b-rows / block.
// ---------------------------------------------------------------------------
__global__ __launch_bounds__(256) void k_proj(const float* __restrict__ mo,
                                              const float* __restrict__ wt,
                                              const float* __restrict__ bias,
                                              float* __restrict__ out) {
    int tid = threadIdx.x;
    int o = (blockIdx.x & 1) * 256 + tid;
    int bb = (blockIdx.x >> 1) * 8;
    float acc[8];
    #pragma unroll
    for (int r = 0; r < 8; r++) acc[r] = 0.f;
    for (int h = 0; h < HID; h++) {
        float wv = wt[(size_t)h * HID + o];
        #pragma unroll
        for (int r = 0; r < 8; r++)
            acc[r] += mo[(size_t)(bb + r) * HID + h] * wv;
    }
    float bv = bias[o];
    #pragma unroll
    for (int r = 0; r < 8; r++)
        out[(size_t)(bb + r) * HID + o] = acc[r] + bv;
}

// ---------------------------------------------------------------------------
extern "C" void kernel_launch(void* const* d_in, const int* in_sizes, int n_in,
                              void* d_out, int out_size, void* d_ws, size_t ws_size,
                              hipStream_t stream) {
    const float* query = (const float*)d_in[0];
    const float* keys  = (const float*)d_in[1];
    const float* vals  = (const float*)d_in[2];
    const float* proj  = (const float*)d_in[3];
    const float* outw  = (const float*)d_in[4];
    const float* outbp = (const float*)d_in[5];
    float* out = (float*)d_out;

    char* ws = (char*)d_ws;
    double*        psumT      = (double*)(ws + 0);              // 32 KB
    unsigned char* qhash      = (unsigned char*)(ws + 32768);   // 2 KB
    unsigned char* khash      = (unsigned char*)(ws + 34816);   // 64 KB
    u32*           hist16     = (u32*)(ws + 100352);            // 16 KB
    u32*           bucketCnt  = (u32*)(ws + 116736);            // 1 KB
    u32*           bucketOff  = (u32*)(ws + 117760);            // 1 KB
    u32*           off16      = (u32*)(ws + 118784);            // 16 KB
    u32*           bucketList = (u32*)(ws + 135168);            // 256 KB
    float*         mo         = (float*)(ws + 397312);          // 4 MB
    float*         wt         = (float*)(ws + 4591616);         // 1 MB
    (void)in_sizes; (void)n_in; (void)out_size; (void)ws_size;

    k_prep<<<66, 256, 0, stream>>>(proj, psumT, hist16, outw, wt);
    k_hash<<<HGRID, 256, 0, stream>>>(query, keys, psumT, qhash, khash, hist16);
    k_scan<<<1, 256, 0, stream>>>(hist16, bucketCnt, bucketOff, off16);
    k_compact<<<1024, 256, 0, stream>>>(khash, off16, bucketList);
    k_attn<<<BATCH, 256, 0, stream>>>(keys, vals, query, qhash, bucketCnt, bucketOff, bucketList, mo);
    k_proj<<<512, 256, 0, stream>>>(mo, wt, outbp, out);
}